// Round 1
// baseline (389.824 us; speedup 1.0000x reference)
//
#include <hip/hip_runtime.h>

#define N_    16
#define DIN   24
#define DOUT  26
#define CIN   64
#define COUT  128
#define NGRP  8
#define EPS   1e-5f

// ws layout (bytes):
//   [0, 1024)          : float stats[N_][NGRP][2] (sum, sumsq) -- zeroed each launch
//   [1024, 1280)       : 64 B zero block (OOB source for global_load_lds) + pad
//   [1280, 443648)     : fp16 Kf[27][4][4][64][8]  (32x32 MFMA B-fragment order)
//   [458752, 28770304) : fp16 xh[N][24][24][24][64]  (pre-converted x) -- OPTIONAL,
//                        only if ws_size >= XH_END; else fp32 fallback path runs.
#define STATS_OFF 0
#define ZERO_OFF  1024
#define KF_OFF    1280
#define XH_OFF    458752
#define XH_BYTES  ((size_t)N_ * DIN * DIN * DIN * CIN * 2)   // 28,311,552
#define XH_END    ((size_t)XH_OFF + XH_BYTES)                // 28,770,304

typedef _Float16 half8_t  __attribute__((ext_vector_type(8)));
typedef float    f32x16_t __attribute__((ext_vector_type(16)));

typedef __attribute__((address_space(3))) void       lds_void;
typedef __attribute__((address_space(1))) const void glb_void;

__device__ __forceinline__ void gload_lds16(const void* g, void* l) {
    __builtin_amdgcn_global_load_lds((glb_void*)g, (lds_void*)l, 16, 0, 0);
}

// ---- build Kf in 32x32x16 B-fragment order + zero stats + zero block ----
// frag (tap, ckg, nf): element j of lane: k(ci) = ckg*16 + (lane>>5)*8 + j,
// n(co) = nf*32 + (lane&31).   t = ((tap*4 + ckg)*4 + nf)*64 + lane.
__global__ __launch_bounds__(256) void convert_k_kernel(
    const float* __restrict__ K, _Float16* __restrict__ Kf,
    float* __restrict__ stats, float* __restrict__ zbuf)
{
    int t = blockIdx.x * 256 + threadIdx.x;
    if (blockIdx.x == 0 && threadIdx.x < N_ * NGRP * 2) stats[threadIdx.x] = 0.0f;
    if (blockIdx.x == 1 && threadIdx.x < 16) zbuf[threadIdx.x] = 0.0f;
    if (t >= 27 * 4 * 4 * 64) return;
    const int lane = t & 63;
    const int nf   = (t >> 6) & 3;
    const int ckg  = (t >> 8) & 3;
    const int tap  = t >> 10;                        // 0..26 = ad*9+ah*3+aw
    const int ci0  = ckg * 16 + (lane >> 5) * 8;
    const int co   = nf * 32 + (lane & 31);
    half8_t h;
    #pragma unroll
    for (int j = 0; j < 8; ++j)
        h[j] = (_Float16)K[(size_t)(tap * CIN + ci0 + j) * COUT + co];
    *(half8_t*)(Kf + (size_t)t * 8) = h;
}

// ---- x fp32 -> fp16, same [n][d][h][w][ci] layout ----
__global__ __launch_bounds__(256) void convert_x_kernel(
    const float* __restrict__ x, _Float16* __restrict__ xh)
{
    const int TOT = N_ * DIN * DIN * DIN * CIN / 8;  // 1,769,472 half8 chunks
    int i = blockIdx.x * 256 + threadIdx.x;
    if (i >= TOT) return;
    const float4 a = ((const float4*)x)[(size_t)i * 2];
    const float4 b = ((const float4*)x)[(size_t)i * 2 + 1];
    half8_t v;
    v[0] = (_Float16)a.x; v[1] = (_Float16)a.y; v[2] = (_Float16)a.z; v[3] = (_Float16)a.w;
    v[4] = (_Float16)b.x; v[5] = (_Float16)b.y; v[6] = (_Float16)b.z; v[7] = (_Float16)b.w;
    *(half8_t*)(xh + (size_t)i * 8) = v;
}

// ==== NEW PATH: conv via fp16 x, global_load_lds staging, swizzled LDS ====
// Block = (n, d, h-quad). 4 waves: (wv&1)->h-pair, (wv>>1)->cout-pair.
// LDS row (s = ad*6+hs): 32 slots x 64 B; chunk swizzle: physical chunk wch at
// (slot,wch) holds logical ch = wch ^ ((slot>>1)&3)  (ch = 8-ci group).
// Staging is LINEAR in LDS (chunk c -> byte c*16) so global_load_lds's
// uniform-base+lane*16 rule holds; the swizzle is applied on the SOURCE address
// and again on the ds_read side (involution).  Bank-quad (addr>>4)&7 =
// (slot*4 + wch)&7 covers all 8 quads per 8 slots -> conflict-free b128 reads.
// LDS 36,928 B -> 4 blocks/CU.
__global__ __launch_bounds__(256, 4) void conv_mfma_f16x_kernel(
    const _Float16* __restrict__ xh, const _Float16* __restrict__ Kf,
    float* __restrict__ y, float* __restrict__ stats, const float* __restrict__ zbuf)
{
    __shared__ __align__(16) _Float16 xs[18 * 32 * 32];   // 36,864 B
    __shared__ float gsum[NGRP], gsq[NGRP];

    const int bid = blockIdx.x;
    const int n   = bid / (DOUT * 7);
    const int rem = bid % (DOUT * 7);
    const int d   = rem / 7;
    const int hb  = (rem % 7) * 4;
    const int tid = threadIdx.x;

    if (tid < NGRP) { gsum[tid] = 0.0f; gsq[tid] = 0.0f; }

    const int lane = tid & 63;
    const int wv   = tid >> 6;
    const int hp   = wv & 1;            // h-pair: rows hb+2*hp, hb+2*hp+1
    const int nfp  = wv >> 1;           // cout frags nfp*2, nfp*2+1 (32 couts each)
    const int col  = lane & 31;         // A: m(=w) ; B/C/D: n(cout in frag)
    const int hi   = lane >> 5;         // k-half selector

    // per-lane swizzled read offsets within an LDS row, ofs[aw][ck]
    int ofs[3][2];
    #pragma unroll
    for (int aw = 0; aw < 3; ++aw) {
        int sl = col - aw + 2; if (sl > 31) sl = 31;   // slots 28..31 always zero
        #pragma unroll
        for (int ck = 0; ck < 2; ++ck) {
            const int ch = hi + 2 * ck;                // logical 8-ci group
            ofs[aw][ck] = sl * 64 + ((ch ^ ((sl >> 1) & 3)) * 16);
        }
    }

    f32x16_t acc[2][2];
    #pragma unroll
    for (int mt = 0; mt < 2; ++mt)
        #pragma unroll
        for (int fi = 0; fi < 2; ++fi) acc[mt][fi] = (f32x16_t)(0.0f);

    const char* xsb = (const char*)xs + hp * 4096;

    for (int ph = 0; ph < 2; ++ph) {
        // ---- stage this phase's 32 ci: 18 rows x 128 chunks = 2304 DMAs ----
        #pragma unroll
        for (int k = 0; k < 9; ++k) {
            const int c    = tid + k * 256;
            const int s    = c >> 7;                 // row = ad*6 + hs
            const int r    = c & 127;
            const int slot = r >> 2;
            const int wch  = r & 3;                  // physical chunk
            const int ch   = wch ^ ((slot >> 1) & 3);// logical 8-ci group
            const int dd = d - s / 6;
            const int hh = hb + (s % 6) - 2;
            const int w  = slot - 2;
            const void* src;
            if ((unsigned)dd < DIN && (unsigned)hh < DIN && (unsigned)w < DIN)
                src = xh + ((((size_t)n * DIN + dd) * DIN + hh) * DIN + w) * CIN
                         + ph * 32 + ch * 8;
            else
                src = zbuf;
            gload_lds16(src, (char*)xs + (size_t)c * 16);
        }
        __syncthreads();   // compiler drains vmcnt (global_load_lds) before barrier

        // ---- all 27 taps x 2 k16-steps within this ci-half ----
        const _Float16* Kfp = Kf + (size_t)lane * 8 + (size_t)(ph * 8 + nfp * 2) * 512;
        for (int ad = 0; ad < 3; ++ad) {
            for (int ah = 0; ah < 3; ++ah) {
                const int s0b = (ad * 6 - ah + 2) * 2048;   // + hp*4096 in xsb
                const int tap = (ad * 3 + ah) * 3;
                #pragma unroll
                for (int aw = 0; aw < 3; ++aw) {
                    const _Float16* Bt = Kfp + (size_t)((tap + aw) * 16) * 512;
                    #pragma unroll
                    for (int ck = 0; ck < 2; ++ck) {
                        half8_t a0 = *(const half8_t*)(xsb + s0b + ofs[aw][ck]);
                        half8_t a1 = *(const half8_t*)(xsb + s0b + 2048 + ofs[aw][ck]);
                        half8_t b0 = *(const half8_t*)(Bt + (size_t)(ck * 4) * 512);
                        half8_t b1 = *(const half8_t*)(Bt + (size_t)(ck * 4 + 1) * 512);
                        acc[0][0] = __builtin_amdgcn_mfma_f32_32x32x16_f16(a0, b0, acc[0][0], 0, 0, 0);
                        acc[0][1] = __builtin_amdgcn_mfma_f32_32x32x16_f16(a0, b1, acc[0][1], 0, 0, 0);
                        acc[1][0] = __builtin_amdgcn_mfma_f32_32x32x16_f16(a1, b0, acc[1][0], 0, 0, 0);
                        acc[1][1] = __builtin_amdgcn_mfma_f32_32x32x16_f16(a1, b1, acc[1][1], 0, 0, 0);
                    }
                }
            }
        }
        if (ph == 0) __syncthreads();   // protect LDS before re-staging
    }

    // epilogue. C/D (HW-verified): col(cout)=lane&31, row(w)=(reg&3)+8*(reg>>2)+4*hi
    #pragma unroll
    for (int mt = 0; mt < 2; ++mt) {
        const int hrow = hb + 2 * hp + mt;
        if (hrow >= DOUT) continue;
        const size_t rowbase = (((size_t)(n * DOUT + d)) * DOUT + hrow) * (DOUT * COUT);
        #pragma unroll
        for (int fi = 0; fi < 2; ++fi) {
            const int fr   = nfp * 2 + fi;
            const int cout = fr * 32 + col;
            float ls = 0.f, lsq = 0.f;
            #pragma unroll
            for (int reg = 0; reg < 16; ++reg) {
                const int wout = (reg & 3) + 8 * (reg >> 2) + 4 * hi;
                float v = fmaxf(acc[mt][fi][reg], 0.0f);
                if (wout < DOUT) {
                    y[rowbase + (size_t)wout * COUT + cout] = v;
                    ls += v; lsq += v * v;
                }
            }
            #pragma unroll
            for (int off = 1; off < 16; off <<= 1) {
                ls  += __shfl_xor(ls, off);
                lsq += __shfl_xor(lsq, off);
            }
            ls  += __shfl_xor(ls, 32);
            lsq += __shfl_xor(lsq, 32);
            if (lane == 0 || lane == 16) {
                const int g = fr * 2 + (col >> 4);   // 8 groups of 16 couts
                atomicAdd(&gsum[g], ls);
                atomicAdd(&gsq[g], lsq);
            }
        }
    }
    __syncthreads();
    if (tid < NGRP) {
        atomicAdd(&stats[(n * NGRP + tid) * 2 + 0], gsum[tid]);
        atomicAdd(&stats[(n * NGRP + tid) * 2 + 1], gsq[tid]);
    }
}

// ==== FALLBACK PATH (verbatim round-7 kernel): fp32 x, reg-staged LDS ====
__global__ __launch_bounds__(256, 4) void conv_mfma_kernel(
    const float* __restrict__ x, const _Float16* __restrict__ Kf,
    float* __restrict__ y, float* __restrict__ stats)
{
    __shared__ __align__(16) _Float16 xs[18 * 28 * 40];   // 40,320 B
    __shared__ float gsum[NGRP], gsq[NGRP];

    const int bid = blockIdx.x;
    const int n   = bid / (DOUT * 7);
    const int rem = bid % (DOUT * 7);
    const int d   = rem / 7;
    const int hb  = (rem % 7) * 4;
    const int tid = threadIdx.x;

    if (tid < NGRP) { gsum[tid] = 0.0f; gsq[tid] = 0.0f; }

    const int lane = tid & 63;
    const int wv   = tid >> 6;
    const int hp   = wv & 1;
    const int nfp  = wv >> 1;
    const int col  = lane & 31;
    const int hi   = lane >> 5;

    int aofs[3];
    #pragma unroll
    for (int aw = 0; aw < 3; ++aw) {
        int sl = col - aw + 2; if (sl > 27) sl = 27;
        aofs[aw] = sl * 40 + hi * 8;
    }

    f32x16_t acc[2][2];
    #pragma unroll
    for (int mt = 0; mt < 2; ++mt)
        #pragma unroll
        for (int fi = 0; fi < 2; ++fi) acc[mt][fi] = (f32x16_t)(0.0f);

    const _Float16* Kfl = Kf + (size_t)lane * 8;

    for (int ph = 0; ph < 2; ++ph) {
        for (int c = tid; c < 2016; c += 256) {
            const int s    = c / 112;
            const int rr   = c % 112;
            const int slot = rr >> 2;
            const int ch   = rr & 3;
            const int dd = d - s / 6;
            const int hh = hb + (s % 6) - 2;
            const int w  = slot - 2;
            half8_t v = {};
            if (dd >= 0 && dd < DIN && hh >= 0 && hh < DIN && w >= 0 && w < DIN) {
                const float* src = x + ((size_t)(((n * DIN + dd) * DIN + hh) * DIN + w)) * CIN
                                     + ph * 32 + ch * 8;
                const float4 a = *(const float4*)(src);
                const float4 b = *(const float4*)(src + 4);
                v[0] = (_Float16)a.x; v[1] = (_Float16)a.y; v[2] = (_Float16)a.z; v[3] = (_Float16)a.w;
                v[4] = (_Float16)b.x; v[5] = (_Float16)b.y; v[6] = (_Float16)b.z; v[7] = (_Float16)b.w;
            }
            *(half8_t*)(xs + s * 1120 + slot * 40 + ch * 8) = v;
        }
        __syncthreads();

        for (int ad = 0; ad < 3; ++ad) {
            for (int ah = 0; ah < 3; ++ah) {
                const int s0  = (ad * 6 + 2 * hp - ah + 2) * 1120;
                const int s1  = s0 + 1120;
                const int tap = (ad * 3 + ah) * 3;
                #pragma unroll
                for (int aw = 0; aw < 3; ++aw) {
                    const _Float16* Bt = Kfl + (size_t)(((tap + aw) * 4 + ph * 2) * 4 + nfp * 2) * 512;
                    #pragma unroll
                    for (int ck = 0; ck < 2; ++ck) {
                        half8_t a0 = *(const half8_t*)(xs + s0 + aofs[aw] + ck * 16);
                        half8_t a1 = *(const half8_t*)(xs + s1 + aofs[aw] + ck * 16);
                        half8_t b0 = *(const half8_t*)(Bt + (size_t)(ck * 4) * 512);
                        half8_t b1 = *(const half8_t*)(Bt + (size_t)(ck * 4 + 1) * 512);
                        acc[0][0] = __builtin_amdgcn_mfma_f32_32x32x16_f16(a0, b0, acc[0][0], 0, 0, 0);
                        acc[0][1] = __builtin_amdgcn_mfma_f32_32x32x16_f16(a0, b1, acc[0][1], 0, 0, 0);
                        acc[1][0] = __builtin_amdgcn_mfma_f32_32x32x16_f16(a1, b0, acc[1][0], 0, 0, 0);
                        acc[1][1] = __builtin_amdgcn_mfma_f32_32x32x16_f16(a1, b1, acc[1][1], 0, 0, 0);
                    }
                }
            }
        }
        if (ph == 0) __syncthreads();
    }

    #pragma unroll
    for (int mt = 0; mt < 2; ++mt) {
        const int hrow = hb + 2 * hp + mt;
        if (hrow >= DOUT) continue;
        const size_t rowbase = (((size_t)(n * DOUT + d)) * DOUT + hrow) * (DOUT * COUT);
        #pragma unroll
        for (int fi = 0; fi < 2; ++fi) {
            const int fr   = nfp * 2 + fi;
            const int cout = fr * 32 + col;
            float ls = 0.f, lsq = 0.f;
            #pragma unroll
            for (int reg = 0; reg < 16; ++reg) {
                const int wout = (reg & 3) + 8 * (reg >> 2) + 4 * hi;
                float v = fmaxf(acc[mt][fi][reg], 0.0f);
                if (wout < DOUT) {
                    y[rowbase + (size_t)wout * COUT + cout] = v;
                    ls += v; lsq += v * v;
                }
            }
            #pragma unroll
            for (int off = 1; off < 16; off <<= 1) {
                ls  += __shfl_xor(ls, off);
                lsq += __shfl_xor(lsq, off);
            }
            ls  += __shfl_xor(ls, 32);
            lsq += __shfl_xor(lsq, 32);
            if (lane == 0 || lane == 16) {
                const int g = fr * 2 + (col >> 4);
                atomicAdd(&gsum[g], ls);
                atomicAdd(&gsq[g], lsq);
            }
        }
    }
    __syncthreads();
    if (tid < NGRP) {
        atomicAdd(&stats[(n * NGRP + tid) * 2 + 0], gsum[tid]);
        atomicAdd(&stats[(n * NGRP + tid) * 2 + 1], gsq[tid]);
    }
}

// ---- elementwise normalize ----
__global__ __launch_bounds__(256) void gn_apply_kernel(
    float* __restrict__ y, const float* __restrict__ stats,
    const float* __restrict__ scale, const float* __restrict__ bias)
{
    const int total4 = N_ * DOUT * DOUT * DOUT * (COUT / 4);
    int i = blockIdx.x * 256 + threadIdx.x;
    if (i >= total4) return;

    const int t  = i & 31;
    const int co = t * 4;
    const int g  = t >> 2;
    const int n  = i / (DOUT * DOUT * DOUT * (COUT / 4));

    const float s  = stats[(n * NGRP + g) * 2 + 0];
    const float sq = stats[(n * NGRP + g) * 2 + 1];
    const float invN = 1.0f / (float)(DOUT * DOUT * DOUT * (COUT / NGRP));
    const float mean = s * invN;
    const float var  = sq * invN - mean * mean;
    const float rstd = rsqrtf(var + EPS);

    float4 v = ((float4*)y)[i];
    const float4 sc = *(const float4*)(scale + co);
    const float4 bi = *(const float4*)(bias + co);
    v.x = (v.x - mean) * rstd * sc.x + bi.x;
    v.y = (v.y - mean) * rstd * sc.y + bi.y;
    v.z = (v.z - mean) * rstd * sc.z + bi.z;
    v.w = (v.w - mean) * rstd * sc.w + bi.w;
    ((float4*)y)[i] = v;
}

extern "C" void kernel_launch(void* const* d_in, const int* in_sizes, int n_in,
                              void* d_out, int out_size, void* d_ws, size_t ws_size,
                              hipStream_t stream) {
    const float* x     = (const float*)d_in[0];
    const float* K     = (const float*)d_in[1];
    const float* scale = (const float*)d_in[2];
    const float* bias  = (const float*)d_in[3];
    float* y = (float*)d_out;

    float*    stats = (float*)((char*)d_ws + STATS_OFF);
    float*    zbuf  = (float*)((char*)d_ws + ZERO_OFF);
    _Float16* Kf    = (_Float16*)((char*)d_ws + KF_OFF);
    _Float16* xh    = (_Float16*)((char*)d_ws + XH_OFF);

    convert_k_kernel<<<108, 256, 0, stream>>>(K, Kf, stats, zbuf);

    if (ws_size >= XH_END) {
        const int xtot = N_ * DIN * DIN * DIN * CIN / 8;           // 1,769,472
        convert_x_kernel<<<(xtot + 255) / 256, 256, 0, stream>>>(x, xh);
        conv_mfma_f16x_kernel<<<N_ * DOUT * 7, 256, 0, stream>>>(xh, Kf, y, stats, zbuf);
    } else {
        conv_mfma_kernel<<<N_ * DOUT * 7, 256, 0, stream>>>(x, Kf, y, stats);
    }

    const int total4 = N_ * DOUT * DOUT * DOUT * (COUT / 4);
    gn_apply_kernel<<<(total4 + 255) / 256, 256, 0, stream>>>(y, stats, scale, bias);
}

// Round 2
// 372.236 us; speedup vs baseline: 1.0473x; 1.0473x over previous
//
#include <hip/hip_runtime.h>

#define N_    16
#define DIN   24
#define DOUT  26
#define CIN   64
#define COUT  128
#define NGRP  8
#define EPS   1e-5f

// ws layout (bytes):
//   [0, 1024)          : float stats[N_][NGRP][2] (sum, sumsq) -- zeroed each launch
//   [1280, 443648)     : fp16 Kf[27][4][4][64][8]  (32x32 MFMA B-fragment order)
//   [458752, 28770304) : fp16 xh[N][24][24][24][64] (pre-converted x) -- used only
//                        if ws_size >= XH_END; else fp32 fallback path runs.
#define STATS_OFF 0
#define KF_OFF    1280
#define XH_OFF    458752
#define XH_BYTES  ((size_t)N_ * DIN * DIN * DIN * CIN * 2)   // 28,311,552
#define XH_END    ((size_t)XH_OFF + XH_BYTES)                // 28,770,304

typedef _Float16 half8_t  __attribute__((ext_vector_type(8)));
typedef float    f32x16_t __attribute__((ext_vector_type(16)));

// ---- build Kf in 32x32x16 B-fragment order + zero stats ----
// frag (tap, ckg, nf): element j of lane: k(ci) = ckg*16 + (lane>>5)*8 + j,
// n(co) = nf*32 + (lane&31).   t = ((tap*4 + ckg)*4 + nf)*64 + lane.
__global__ __launch_bounds__(256) void convert_k_kernel(
    const float* __restrict__ K, _Float16* __restrict__ Kf, float* __restrict__ stats)
{
    int t = blockIdx.x * 256 + threadIdx.x;
    if (blockIdx.x == 0 && threadIdx.x < N_ * NGRP * 2) stats[threadIdx.x] = 0.0f;
    if (t >= 27 * 4 * 4 * 64) return;
    const int lane = t & 63;
    const int nf   = (t >> 6) & 3;
    const int ckg  = (t >> 8) & 3;
    const int tap  = t >> 10;                        // 0..26 = ad*9+ah*3+aw
    const int ci0  = ckg * 16 + (lane >> 5) * 8;
    const int co   = nf * 32 + (lane & 31);
    half8_t h;
    #pragma unroll
    for (int j = 0; j < 8; ++j)
        h[j] = (_Float16)K[(size_t)(tap * CIN + ci0 + j) * COUT + co];
    *(half8_t*)(Kf + (size_t)t * 8) = h;
}

// ---- x fp32 -> fp16, same [n][d][h][w][ci] layout ----
__global__ __launch_bounds__(256) void convert_x_kernel(
    const float* __restrict__ x, _Float16* __restrict__ xh)
{
    const int TOT = N_ * DIN * DIN * DIN * CIN / 8;  // 1,769,472 half8 chunks
    int i = blockIdx.x * 256 + threadIdx.x;
    if (i >= TOT) return;
    const float4 a = ((const float4*)x)[(size_t)i * 2];
    const float4 b = ((const float4*)x)[(size_t)i * 2 + 1];
    half8_t v;
    v[0] = (_Float16)a.x; v[1] = (_Float16)a.y; v[2] = (_Float16)a.z; v[3] = (_Float16)a.w;
    v[4] = (_Float16)b.x; v[5] = (_Float16)b.y; v[6] = (_Float16)b.z; v[7] = (_Float16)b.w;
    *(half8_t*)(xh + (size_t)i * 8) = v;
}

// ==== MAIN PATH: round-7 structure, fp16 x source, ah-unrolled tap loop ====
// Block = (n, d, h-quad). 4 waves: (wv&1)->h-pair, (wv>>1)->cout-pair.
// Phase ph in {0,1}: stage ci ph*32..ph*32+31 for all 18 (ad,hh) rows, barrier,
// run all 27 taps x 2 k16-steps; acc persists across phases.
// LDS row: 28 w-slots; slot stride 40 half (32 ci data + 8 pad; 80 B keeps
// b128 16-B aligned). 40,320 B LDS.
__global__ __launch_bounds__(256, 4) void conv_mfma_h_kernel(
    const _Float16* __restrict__ xh, const _Float16* __restrict__ Kf,
    float* __restrict__ y, float* __restrict__ stats)
{
    __shared__ __align__(16) _Float16 xs[18 * 28 * 40];   // 40,320 B
    __shared__ float gsum[NGRP], gsq[NGRP];

    const int bid = blockIdx.x;
    const int n   = bid / (DOUT * 7);
    const int rem = bid % (DOUT * 7);
    const int d   = rem / 7;
    const int hb  = (rem % 7) * 4;
    const int tid = threadIdx.x;

    if (tid < NGRP) { gsum[tid] = 0.0f; gsq[tid] = 0.0f; }

    const int lane = tid & 63;
    const int wv   = tid >> 6;
    const int hp   = wv & 1;            // h-pair: rows hb+2*hp, hb+2*hp+1
    const int nfp  = wv >> 1;           // cout frags nfp*2, nfp*2+1 (32 couts each)
    const int col  = lane & 31;         // A: m(=w) ; B/C/D: n(cout in frag)
    const int hi   = lane >> 5;         // k-half selector

    int aofs[3];
    #pragma unroll
    for (int aw = 0; aw < 3; ++aw) {
        int sl = col - aw + 2; if (sl > 27) sl = 27;   // slot 27 always zero-staged
        aofs[aw] = sl * 40 + hi * 8;
    }

    f32x16_t acc[2][2];
    #pragma unroll
    for (int mt = 0; mt < 2; ++mt)
        #pragma unroll
        for (int fi = 0; fi < 2; ++fi) acc[mt][fi] = (f32x16_t)(0.0f);

    const _Float16* Kfl = Kf + (size_t)lane * 8;

    for (int ph = 0; ph < 2; ++ph) {
        // ---- stage this phase's 32 ci: 18*28*4 = 2016 16-B chunks ----
        // fp16 source: one 16-B load + one ds_write_b128 per chunk, no cvt.
        for (int c = tid; c < 2016; c += 256) {
            const int s    = c / 112;        // s = ad*6 + hs
            const int rr   = c % 112;
            const int slot = rr >> 2;        // source w = slot - 2
            const int ch   = rr & 3;
            const int dd = d - s / 6;
            const int hh = hb + (s % 6) - 2;
            const int w  = slot - 2;
            half8_t v = {};
            if (dd >= 0 && dd < DIN && hh >= 0 && hh < DIN && w >= 0 && w < DIN) {
                v = *(const half8_t*)(xh
                        + ((size_t)(((n * DIN + dd) * DIN + hh) * DIN + w)) * CIN
                        + ph * 32 + ch * 8);
            }
            *(half8_t*)(xs + s * 1120 + slot * 40 + ch * 8) = v;
        }
        __syncthreads();

        // ---- all 27 taps, 2 k16-steps within this ci-half ----
        for (int ad = 0; ad < 3; ++ad) {
            #pragma unroll
            for (int ah = 0; ah < 3; ++ah) {
                const int s0  = (ad * 6 + 2 * hp - ah + 2) * 1120;
                const int s1  = s0 + 1120;
                const int tap = (ad * 3 + ah) * 3;
                #pragma unroll
                for (int aw = 0; aw < 3; ++aw) {
                    const _Float16* Bt = Kfl + (size_t)(((tap + aw) * 4 + ph * 2) * 4 + nfp * 2) * 512;
                    #pragma unroll
                    for (int ck = 0; ck < 2; ++ck) {
                        half8_t a0 = *(const half8_t*)(xs + s0 + aofs[aw] + ck * 16);
                        half8_t a1 = *(const half8_t*)(xs + s1 + aofs[aw] + ck * 16);
                        half8_t b0 = *(const half8_t*)(Bt + (size_t)(ck * 4) * 512);
                        half8_t b1 = *(const half8_t*)(Bt + (size_t)(ck * 4 + 1) * 512);
                        acc[0][0] = __builtin_amdgcn_mfma_f32_32x32x16_f16(a0, b0, acc[0][0], 0, 0, 0);
                        acc[0][1] = __builtin_amdgcn_mfma_f32_32x32x16_f16(a0, b1, acc[0][1], 0, 0, 0);
                        acc[1][0] = __builtin_amdgcn_mfma_f32_32x32x16_f16(a1, b0, acc[1][0], 0, 0, 0);
                        acc[1][1] = __builtin_amdgcn_mfma_f32_32x32x16_f16(a1, b1, acc[1][1], 0, 0, 0);
                    }
                }
            }
        }
        if (ph == 0) __syncthreads();   // protect LDS before re-staging
    }

    // epilogue. C/D (HW-verified): col(cout)=lane&31, row(w)=(reg&3)+8*(reg>>2)+4*hi
    #pragma unroll
    for (int mt = 0; mt < 2; ++mt) {
        const int hrow = hb + 2 * hp + mt;
        if (hrow >= DOUT) continue;
        const size_t rowbase = (((size_t)(n * DOUT + d)) * DOUT + hrow) * (DOUT * COUT);
        #pragma unroll
        for (int fi = 0; fi < 2; ++fi) {
            const int fr   = nfp * 2 + fi;
            const int cout = fr * 32 + col;
            float ls = 0.f, lsq = 0.f;
            #pragma unroll
            for (int reg = 0; reg < 16; ++reg) {
                const int wout = (reg & 3) + 8 * (reg >> 2) + 4 * hi;
                float v = fmaxf(acc[mt][fi][reg], 0.0f);
                if (wout < DOUT) {
                    y[rowbase + (size_t)wout * COUT + cout] = v;
                    ls += v; lsq += v * v;
                }
            }
            // cohort sharing one GN group: same (col>>4) -> xor {1,2,4,8,32}
            #pragma unroll
            for (int off = 1; off < 16; off <<= 1) {
                ls  += __shfl_xor(ls, off);
                lsq += __shfl_xor(lsq, off);
            }
            ls  += __shfl_xor(ls, 32);
            lsq += __shfl_xor(lsq, 32);
            if (lane == 0 || lane == 16) {
                const int g = fr * 2 + (col >> 4);   // 8 groups of 16 couts
                atomicAdd(&gsum[g], ls);
                atomicAdd(&gsq[g], lsq);
            }
        }
    }
    __syncthreads();
    if (tid < NGRP) {
        atomicAdd(&stats[(n * NGRP + tid) * 2 + 0], gsum[tid]);
        atomicAdd(&stats[(n * NGRP + tid) * 2 + 1], gsq[tid]);
    }
}

// ==== FALLBACK PATH (verbatim round-7 kernel): fp32 x, reg-staged LDS ====
__global__ __launch_bounds__(256, 4) void conv_mfma_kernel(
    const float* __restrict__ x, const _Float16* __restrict__ Kf,
    float* __restrict__ y, float* __restrict__ stats)
{
    __shared__ __align__(16) _Float16 xs[18 * 28 * 40];   // 40,320 B
    __shared__ float gsum[NGRP], gsq[NGRP];

    const int bid = blockIdx.x;
    const int n   = bid / (DOUT * 7);
    const int rem = bid % (DOUT * 7);
    const int d   = rem / 7;
    const int hb  = (rem % 7) * 4;
    const int tid = threadIdx.x;

    if (tid < NGRP) { gsum[tid] = 0.0f; gsq[tid] = 0.0f; }

    const int lane = tid & 63;
    const int wv   = tid >> 6;
    const int hp   = wv & 1;
    const int nfp  = wv >> 1;
    const int col  = lane & 31;
    const int hi   = lane >> 5;

    int aofs[3];
    #pragma unroll
    for (int aw = 0; aw < 3; ++aw) {
        int sl = col - aw + 2; if (sl > 27) sl = 27;
        aofs[aw] = sl * 40 + hi * 8;
    }

    f32x16_t acc[2][2];
    #pragma unroll
    for (int mt = 0; mt < 2; ++mt)
        #pragma unroll
        for (int fi = 0; fi < 2; ++fi) acc[mt][fi] = (f32x16_t)(0.0f);

    const _Float16* Kfl = Kf + (size_t)lane * 8;

    for (int ph = 0; ph < 2; ++ph) {
        for (int c = tid; c < 2016; c += 256) {
            const int s    = c / 112;
            const int rr   = c % 112;
            const int slot = rr >> 2;
            const int ch   = rr & 3;
            const int dd = d - s / 6;
            const int hh = hb + (s % 6) - 2;
            const int w  = slot - 2;
            half8_t v = {};
            if (dd >= 0 && dd < DIN && hh >= 0 && hh < DIN && w >= 0 && w < DIN) {
                const float* src = x + ((size_t)(((n * DIN + dd) * DIN + hh) * DIN + w)) * CIN
                                     + ph * 32 + ch * 8;
                const float4 a = *(const float4*)(src);
                const float4 b = *(const float4*)(src + 4);
                v[0] = (_Float16)a.x; v[1] = (_Float16)a.y; v[2] = (_Float16)a.z; v[3] = (_Float16)a.w;
                v[4] = (_Float16)b.x; v[5] = (_Float16)b.y; v[6] = (_Float16)b.z; v[7] = (_Float16)b.w;
            }
            *(half8_t*)(xs + s * 1120 + slot * 40 + ch * 8) = v;
        }
        __syncthreads();

        for (int ad = 0; ad < 3; ++ad) {
            for (int ah = 0; ah < 3; ++ah) {
                const int s0  = (ad * 6 + 2 * hp - ah + 2) * 1120;
                const int s1  = s0 + 1120;
                const int tap = (ad * 3 + ah) * 3;
                #pragma unroll
                for (int aw = 0; aw < 3; ++aw) {
                    const _Float16* Bt = Kfl + (size_t)(((tap + aw) * 4 + ph * 2) * 4 + nfp * 2) * 512;
                    #pragma unroll
                    for (int ck = 0; ck < 2; ++ck) {
                        half8_t a0 = *(const half8_t*)(xs + s0 + aofs[aw] + ck * 16);
                        half8_t a1 = *(const half8_t*)(xs + s1 + aofs[aw] + ck * 16);
                        half8_t b0 = *(const half8_t*)(Bt + (size_t)(ck * 4) * 512);
                        half8_t b1 = *(const half8_t*)(Bt + (size_t)(ck * 4 + 1) * 512);
                        acc[0][0] = __builtin_amdgcn_mfma_f32_32x32x16_f16(a0, b0, acc[0][0], 0, 0, 0);
                        acc[0][1] = __builtin_amdgcn_mfma_f32_32x32x16_f16(a0, b1, acc[0][1], 0, 0, 0);
                        acc[1][0] = __builtin_amdgcn_mfma_f32_32x32x16_f16(a1, b0, acc[1][0], 0, 0, 0);
                        acc[1][1] = __builtin_amdgcn_mfma_f32_32x32x16_f16(a1, b1, acc[1][1], 0, 0, 0);
                    }
                }
            }
        }
        if (ph == 0) __syncthreads();
    }

    #pragma unroll
    for (int mt = 0; mt < 2; ++mt) {
        const int hrow = hb + 2 * hp + mt;
        if (hrow >= DOUT) continue;
        const size_t rowbase = (((size_t)(n * DOUT + d)) * DOUT + hrow) * (DOUT * COUT);
        #pragma unroll
        for (int fi = 0; fi < 2; ++fi) {
            const int fr   = nfp * 2 + fi;
            const int cout = fr * 32 + col;
            float ls = 0.f, lsq = 0.f;
            #pragma unroll
            for (int reg = 0; reg < 16; ++reg) {
                const int wout = (reg & 3) + 8 * (reg >> 2) + 4 * hi;
                float v = fmaxf(acc[mt][fi][reg], 0.0f);
                if (wout < DOUT) {
                    y[rowbase + (size_t)wout * COUT + cout] = v;
                    ls += v; lsq += v * v;
                }
            }
            #pragma unroll
            for (int off = 1; off < 16; off <<= 1) {
                ls  += __shfl_xor(ls, off);
                lsq += __shfl_xor(lsq, off);
            }
            ls  += __shfl_xor(ls, 32);
            lsq += __shfl_xor(lsq, 32);
            if (lane == 0 || lane == 16) {
                const int g = fr * 2 + (col >> 4);
                atomicAdd(&gsum[g], ls);
                atomicAdd(&gsq[g], lsq);
            }
        }
    }
    __syncthreads();
    if (tid < NGRP) {
        atomicAdd(&stats[(n * NGRP + tid) * 2 + 0], gsum[tid]);
        atomicAdd(&stats[(n * NGRP + tid) * 2 + 1], gsq[tid]);
    }
}

// ---- elementwise normalize ----
__global__ __launch_bounds__(256) void gn_apply_kernel(
    float* __restrict__ y, const float* __restrict__ stats,
    const float* __restrict__ scale, const float* __restrict__ bias)
{
    const int total4 = N_ * DOUT * DOUT * DOUT * (COUT / 4);
    int i = blockIdx.x * 256 + threadIdx.x;
    if (i >= total4) return;

    const int t  = i & 31;
    const int co = t * 4;
    const int g  = t >> 2;
    const int n  = i / (DOUT * DOUT * DOUT * (COUT / 4));

    const float s  = stats[(n * NGRP + g) * 2 + 0];
    const float sq = stats[(n * NGRP + g) * 2 + 1];
    const float invN = 1.0f / (float)(DOUT * DOUT * DOUT * (COUT / NGRP));
    const float mean = s * invN;
    const float var  = sq * invN - mean * mean;
    const float rstd = rsqrtf(var + EPS);

    float4 v = ((float4*)y)[i];
    const float4 sc = *(const float4*)(scale + co);
    const float4 bi = *(const float4*)(bias + co);
    v.x = (v.x - mean) * rstd * sc.x + bi.x;
    v.y = (v.y - mean) * rstd * sc.y + bi.y;
    v.z = (v.z - mean) * rstd * sc.z + bi.z;
    v.w = (v.w - mean) * rstd * sc.w + bi.w;
    ((float4*)y)[i] = v;
}

extern "C" void kernel_launch(void* const* d_in, const int* in_sizes, int n_in,
                              void* d_out, int out_size, void* d_ws, size_t ws_size,
                              hipStream_t stream) {
    const float* x     = (const float*)d_in[0];
    const float* K     = (const float*)d_in[1];
    const float* scale = (const float*)d_in[2];
    const float* bias  = (const float*)d_in[3];
    float* y = (float*)d_out;

    float*    stats = (float*)((char*)d_ws + STATS_OFF);
    _Float16* Kf    = (_Float16*)((char*)d_ws + KF_OFF);
    _Float16* xh    = (_Float16*)((char*)d_ws + XH_OFF);

    convert_k_kernel<<<108, 256, 0, stream>>>(K, Kf, stats);

    if (ws_size >= XH_END) {
        const int xtot = N_ * DIN * DIN * DIN * CIN / 8;           // 1,769,472
        convert_x_kernel<<<(xtot + 255) / 256, 256, 0, stream>>>(x, xh);
        conv_mfma_h_kernel<<<N_ * DOUT * 7, 256, 0, stream>>>(xh, Kf, y, stats);
    } else {
        conv_mfma_kernel<<<N_ * DOUT * 7, 256, 0, stream>>>(x, Kf, y, stats);
    }

    const int total4 = N_ * DOUT * DOUT * DOUT * (COUT / 4);
    gn_apply_kernel<<<(total4 + 255) / 256, 256, 0, stream>>>(y, stats, scale, bias);
}